// Round 1
// baseline (93.618 us; speedup 1.0000x reference)
//
#include <hip/hip_runtime.h>
#include <hip/hip_bf16.h>

// CubicalLayer gather: out[i] = X[idx[i].x * W + idx[i].y]
// H = W = 4096, N_IDX = 524288. Output is flat 524288 fp32 (reshape(-1,2)
// is a no-op on flat layout).

#define W_DIM 4096
#define N_IDX 524288

__global__ __launch_bounds__(256) void cubical_gather_kernel(
    const float* __restrict__ X,
    const int2* __restrict__ idx,
    float* __restrict__ out,
    int n)
{
    int i = blockIdx.x * blockDim.x + threadIdx.x;
    if (i < n) {
        int2 p = idx[i];                     // coalesced 8B/lane load
        // row*4096 + col; row,col in [0,4096) so fits in 32-bit (max 2^24)
        out[i] = X[(p.x << 12) + p.y];       // random gather, L2/L3 absorbs reuse
    }
}

extern "C" void kernel_launch(void* const* d_in, const int* in_sizes, int n_in,
                              void* d_out, int out_size, void* d_ws, size_t ws_size,
                              hipStream_t stream) {
    const float* X   = (const float*)d_in[0];
    const int2*  idx = (const int2*)d_in[1];   // (N_IDX, 2) int32 -> int2 pairs
    float* out = (float*)d_out;

    int n = in_sizes[1] / 2;                   // 524288 gather points
    int block = 256;
    int grid = (n + block - 1) / block;        // 2048 blocks
    cubical_gather_kernel<<<grid, block, 0, stream>>>(X, idx, out, n);
}